// Round 1
// baseline (729.643 us; speedup 1.0000x reference)
//
#include <hip/hip_runtime.h>
#include <hip/hip_bf16.h>
#include <math.h>

#define NB 4
#define IMG 192
#define HW (IMG*IMG)        // 36864
#define T_TOT (NB*HW)       // 147456
#define HID 512
#define NWB 2304            // total windows
#define WPB 576             // windows per batch
#define NWS 24              // windows per side

typedef __bf16 bf16;
typedef __bf16 bf8 __attribute__((ext_vector_type(8)));
typedef float f32x4 __attribute__((ext_vector_type(4)));

#define MFMA(a,b,c) __builtin_amdgcn_mfma_f32_16x16x32_bf16(a,b,c,0,0,0)

__device__ __forceinline__ int swz128(int row, int col){ return row*128 + (col ^ ((row&7)<<3)); }
__device__ __forceinline__ int swz64 (int row, int col){ return row*64  + (col ^ ((row&7)<<3)); }

__device__ __forceinline__ bf8 zero_bf8(){
  bf8 z = { (bf16)0.f,(bf16)0.f,(bf16)0.f,(bf16)0.f,(bf16)0.f,(bf16)0.f,(bf16)0.f,(bf16)0.f };
  return z;
}
__device__ __forceinline__ f32x4 zero_f4(){ f32x4 z = {0.f,0.f,0.f,0.f}; return z; }

// ---------------- kernel 0: f32 -> bf16 weight conversion ----------------
__global__ void k_cvt(const float* __restrict__ s, bf16* __restrict__ d, int n){
  int i = blockIdx.x*256 + threadIdx.x;
  if (i < n) d[i] = (bf16)s[i];
}

// ---------------- kernel 1: LN1 + window partition + ce ------------------
// one wave per token; writes xn (window-major bf16) and ce (window-major bf16)
__global__ __launch_bounds__(256) void k_ln1(
    const float* __restrict__ x, const float* __restrict__ cor,
    const float* __restrict__ cor_w, const float* __restrict__ n1w, const float* __restrict__ n1b,
    bf16* __restrict__ xn, bf16* __restrict__ ce)
{
  int wm = threadIdx.x >> 6, l = threadIdx.x & 63;
  int t = blockIdx.x*4 + wm;
  float2 xv = *(const float2*)(x + (size_t)t*128 + 2*l);
  float s = xv.x + xv.y, sq = xv.x*xv.x + xv.y*xv.y;
  #pragma unroll
  for (int m=1;m<64;m<<=1){ s += __shfl_xor(s,m,64); sq += __shfl_xor(sq,m,64); }
  float mean = s * (1.0f/128.0f);
  float var  = sq * (1.0f/128.0f) - mean*mean;
  float rstd = rsqrtf(var + 1e-5f);
  int c = 2*l;
  float y0 = (xv.x-mean)*rstd*n1w[c]   + n1b[c];
  float y1 = (xv.y-mean)*rstd*n1w[c+1] + n1b[c+1];

  int b = t / HW, r = t % HW;
  int yy = r / IMG, xx = r % IMG;
  int win = b*WPB + (yy>>3)*NWS + (xx>>3);
  int n = ((yy&7)<<3) + (xx&7);
  size_t base = (size_t)win*8192 + n*128 + c;

  union { unsigned int u; bf16 h[2]; } pk;
  pk.h[0] = (bf16)y0; pk.h[1] = (bf16)y1;
  *(unsigned int*)(xn + base) = pk.u;

  float c0 = cor[(size_t)t*2], c1 = cor[(size_t)t*2+1];
  float4 w4 = *(const float4*)(cor_w + 4*l);
  pk.h[0] = (bf16)(c0*w4.x + c1*w4.y);
  pk.h[1] = (bf16)(c0*w4.z + c1*w4.w);
  *(unsigned int*)(ce + base) = pk.u;
}

// ---------------- kernel 2: fused window attention -----------------------
__global__ __launch_bounds__(256) void k_attn(
    const bf16* __restrict__ xn, const bf16* __restrict__ ce,
    const bf16* __restrict__ wq, const bf16* __restrict__ wkv,
    const bf16* __restrict__ wpj, const bf16* __restrict__ wmp,
    const float* __restrict__ proj_b, const float* __restrict__ mproj_b,
    const float* __restrict__ x_in, float* __restrict__ x1, float* __restrict__ out_m)
{
  __shared__ __align__(16) bf16 s_stage[64*128];
  __shared__ __align__(16) bf16 s_q [64*128];
  __shared__ __align__(16) bf16 s_k [64*128];
  __shared__ __align__(16) bf16 s_vT[128*64];
  __shared__ __align__(16) bf16 s_ceT[128*64];
  __shared__ __align__(16) bf16 s_xo[64*128];
  __shared__ __align__(16) bf16 s_cm[64*128];
  __shared__ __align__(16) bf16 s_P [64*64];

  int tid = threadIdx.x, wm = tid>>6, l = tid&63;
  int lr = l & 15, lg = l >> 4;
  int win = blockIdx.x;
  int partner = (win + NWB/2) % NWB;
  const bf16* xw_g = xn + (size_t)win*8192;
  const bf16* xr_g = xn + (size_t)partner*8192;
  const bf16* ce_g = ce + (size_t)win*8192;

  // ---- stage xr (swizzled) + ceT (transposed, swizzled) ----
  for (int tci=0;tci<4;tci++){
    int chunk = tid + tci*256;
    int row = chunk>>4, c0 = (chunk&15)*8;
    bf8 v = *(const bf8*)(xr_g + row*128 + c0);
    *(bf8*)&s_stage[swz128(row,c0)] = v;
    bf8 cv = *(const bf8*)(ce_g + row*128 + c0);
    #pragma unroll
    for (int i=0;i<8;i++){
      int chc = c0 + i;
      s_ceT[chc*64 + (row ^ ((chc&7)<<3))] = cv[i];
    }
  }
  __syncthreads();

  // ---- kv GEMM: k -> s_k, v -> s_vT(transposed) ----
  {
    bf8 af[4];
    #pragma unroll
    for (int ks=0;ks<4;ks++) af[ks] = *(const bf8*)&s_stage[swz128(wm*16+lr, ks*32 + lg*8)];
    #pragma unroll
    for (int nt=0;nt<8;nt++){
      f32x4 acc = zero_f4();
      #pragma unroll
      for (int ks=0;ks<4;ks++){
        bf8 bfr = *(const bf8*)(wkv + (nt*16+lr)*128 + ks*32 + lg*8);
        acc = MFMA(af[ks], bfr, acc);
      }
      #pragma unroll
      for (int j=0;j<4;j++){
        int row = wm*16 + lg*4 + j;
        s_k[swz128(row, nt*16+lr)] = (bf16)acc[j];
      }
    }
    #pragma unroll
    for (int nt=0;nt<8;nt++){
      f32x4 acc = zero_f4();
      #pragma unroll
      for (int ks=0;ks<4;ks++){
        bf8 bfr = *(const bf8*)(wkv + (128 + nt*16+lr)*128 + ks*32 + lg*8);
        acc = MFMA(af[ks], bfr, acc);
      }
      #pragma unroll
      for (int j=0;j<4;j++){
        int tok = wm*16 + lg*4 + j;
        int chc = nt*16 + lr;
        s_vT[chc*64 + (tok ^ ((chc&7)<<3))] = (bf16)acc[j];
      }
    }
  }
  __syncthreads();

  // ---- stage xw into s_stage ----
  for (int tci=0;tci<4;tci++){
    int chunk = tid + tci*256;
    int row = chunk>>4, c0 = (chunk&15)*8;
    bf8 v = *(const bf8*)(xw_g + row*128 + c0);
    *(bf8*)&s_stage[swz128(row,c0)] = v;
  }
  __syncthreads();

  // ---- q GEMM -> s_q ----
  {
    bf8 af[4];
    #pragma unroll
    for (int ks=0;ks<4;ks++) af[ks] = *(const bf8*)&s_stage[swz128(wm*16+lr, ks*32 + lg*8)];
    #pragma unroll
    for (int nt=0;nt<8;nt++){
      f32x4 acc = zero_f4();
      #pragma unroll
      for (int ks=0;ks<4;ks++){
        bf8 bfr = *(const bf8*)(wq + (nt*16+lr)*128 + ks*32 + lg*8);
        acc = MFMA(af[ks], bfr, acc);
      }
      #pragma unroll
      for (int j=0;j<4;j++){
        int row = wm*16 + lg*4 + j;
        s_q[swz128(row, nt*16+lr)] = (bf16)acc[j];
      }
    }
  }
  __syncthreads();

  // ---- head loop (barrier-free: each wave owns rows wm*16..wm*16+15) ----
  const float scale = 0.25f;
  for (int h=0;h<8;h++){
    // S = q_h @ k_h^T  (K=16 zero-padded to 32)
    bf8 aS;
    if (l < 32) aS = *(const bf8*)&s_q[swz128(wm*16+lr, h*16 + lg*8)];
    else        aS = zero_bf8();
    f32x4 accS[4];
    #pragma unroll
    for (int nt=0;nt<4;nt++){
      bf8 bS;
      if (l < 32) bS = *(const bf8*)&s_k[swz128(nt*16+lr, h*16 + lg*8)];
      else        bS = zero_bf8();
      accS[nt] = MFMA(aS, bS, zero_f4());
    }
    // softmax per row (row split across 16-lane group x 4 n-tiles)
    #pragma unroll
    for (int j=0;j<4;j++){
      float v0 = accS[0][j]*scale, v1 = accS[1][j]*scale;
      float v2 = accS[2][j]*scale, v3 = accS[3][j]*scale;
      float mx = fmaxf(fmaxf(v0,v1), fmaxf(v2,v3));
      mx = fmaxf(mx, __shfl_xor(mx,1,64));
      mx = fmaxf(mx, __shfl_xor(mx,2,64));
      mx = fmaxf(mx, __shfl_xor(mx,4,64));
      mx = fmaxf(mx, __shfl_xor(mx,8,64));
      float e0 = __expf(v0-mx), e1 = __expf(v1-mx), e2 = __expf(v2-mx), e3 = __expf(v3-mx);
      float sm = e0+e1+e2+e3;
      sm += __shfl_xor(sm,1,64); sm += __shfl_xor(sm,2,64);
      sm += __shfl_xor(sm,4,64); sm += __shfl_xor(sm,8,64);
      float rs = 1.0f / sm;
      int row = wm*16 + lg*4 + j;
      s_P[row*64 + ((lr+ 0) ^ ((row&7)<<3))] = (bf16)(e0*rs);
      s_P[row*64 + ((lr+16) ^ ((row&7)<<3))] = (bf16)(e1*rs);
      s_P[row*64 + ((lr+32) ^ ((row&7)<<3))] = (bf16)(e2*rs);
      s_P[row*64 + ((lr+48) ^ ((row&7)<<3))] = (bf16)(e3*rs);
    }
    // PV and P@ceh
    f32x4 accO = zero_f4(), accC = zero_f4();
    #pragma unroll
    for (int ks=0;ks<2;ks++){
      int rowA = wm*16 + lr;
      bf8 aP = *(const bf8*)&s_P[rowA*64 + ((ks*32 + lg*8) ^ ((rowA&7)<<3))];
      int chc = h*16 + lr;
      bf8 bV = *(const bf8*)&s_vT [chc*64 + ((ks*32 + lg*8) ^ ((chc&7)<<3))];
      accO = MFMA(aP, bV, accO);
      bf8 bC = *(const bf8*)&s_ceT[chc*64 + ((ks*32 + lg*8) ^ ((chc&7)<<3))];
      accC = MFMA(aP, bC, accC);
    }
    #pragma unroll
    for (int j=0;j<4;j++){
      int row = wm*16 + lg*4 + j;
      int col = h*16 + lr;
      s_xo[swz128(row,col)] = (bf16)accO[j];
      float cef = (float)ce_g[row*128 + col];
      s_cm[swz128(row,col)] = (bf16)(accC[j] - cef);
    }
  }
  __syncthreads();

  // ---- proj (+residual, window-reverse) and mproj ----
  int b  = win / WPB, wi = win % WPB;
  int wy = wi / NWS,  wx = wi % NWS;
  {
    bf8 af[4];
    #pragma unroll
    for (int ks=0;ks<4;ks++) af[ks] = *(const bf8*)&s_xo[swz128(wm*16+lr, ks*32 + lg*8)];
    #pragma unroll
    for (int nt=0;nt<8;nt++){
      f32x4 acc = zero_f4();
      #pragma unroll
      for (int ks=0;ks<4;ks++){
        bf8 bfr = *(const bf8*)(wpj + (nt*16+lr)*128 + ks*32 + lg*8);
        acc = MFMA(af[ks], bfr, acc);
      }
      int col = nt*16 + lr;
      float pb = proj_b[col];
      #pragma unroll
      for (int j=0;j<4;j++){
        int tok = wm*16 + lg*4 + j;
        int yy = wy*8 + (tok>>3), xx = wx*8 + (tok&7);
        size_t addr = ((size_t)b*HW + yy*IMG + xx)*128 + col;
        x1[addr] = acc[j] + pb + x_in[addr];
      }
    }
  }
  {
    bf8 af[4];
    #pragma unroll
    for (int ks=0;ks<4;ks++) af[ks] = *(const bf8*)&s_cm[swz128(wm*16+lr, ks*32 + lg*8)];
    #pragma unroll
    for (int nt=0;nt<8;nt++){
      f32x4 acc = zero_f4();
      #pragma unroll
      for (int ks=0;ks<4;ks++){
        bf8 bfr = *(const bf8*)(wmp + (nt*16+lr)*128 + ks*32 + lg*8);
        acc = MFMA(af[ks], bfr, acc);
      }
      int col = nt*16 + lr;
      float pb = mproj_b[col];
      #pragma unroll
      for (int j=0;j<4;j++){
        int tok = wm*16 + lg*4 + j;
        int yy = wy*8 + (tok>>3), xx = wx*8 + (tok&7);
        size_t addr = ((size_t)b*HW + yy*IMG + xx)*128 + col;
        out_m[addr] = acc[j] + pb;
      }
    }
  }
}

// ---------------- kernel 3: LN2 + fc1 ------------------------------------
__global__ __launch_bounds__(256) void k_fc1(
    const float* __restrict__ x1, const float* __restrict__ n2w, const float* __restrict__ n2b,
    const bf16* __restrict__ wf1, const float* __restrict__ fc1b, bf16* __restrict__ h)
{
  __shared__ __align__(16) bf16 s_a[64*128];
  int tid = threadIdx.x, wm = tid>>6, l = tid&63;
  int lr = l & 15, lg = l >> 4;
  size_t t0 = (size_t)blockIdx.x * 64;

  for (int i=0;i<16;i++){
    int tl = wm*16 + i;
    float2 xv = *(const float2*)(x1 + (t0+tl)*128 + 2*l);
    float s = xv.x+xv.y, sq = xv.x*xv.x+xv.y*xv.y;
    #pragma unroll
    for (int m=1;m<64;m<<=1){ s += __shfl_xor(s,m,64); sq += __shfl_xor(sq,m,64); }
    float mean = s*(1.f/128.f), var = sq*(1.f/128.f) - mean*mean;
    float rstd = rsqrtf(var + 1e-5f);
    int c = 2*l;
    union { unsigned int u; bf16 hh[2]; } pk;
    pk.hh[0] = (bf16)((xv.x-mean)*rstd*n2w[c]   + n2b[c]);
    pk.hh[1] = (bf16)((xv.y-mean)*rstd*n2w[c+1] + n2b[c+1]);
    *(unsigned int*)&s_a[swz128(tl,c)] = pk.u;
  }
  __syncthreads();

  bf8 af[4];
  #pragma unroll
  for (int ks=0;ks<4;ks++) af[ks] = *(const bf8*)&s_a[swz128(wm*16+lr, ks*32 + lg*8)];
  for (int ntb=0; ntb<4; ntb++){
    f32x4 acc[8];
    #pragma unroll
    for (int q8=0;q8<8;q8++){
      acc[q8] = zero_f4();
      #pragma unroll
      for (int ks=0;ks<4;ks++){
        int ocol = ntb*128 + q8*16 + lr;
        bf8 bfr = *(const bf8*)(wf1 + (size_t)ocol*128 + ks*32 + lg*8);
        acc[q8] = MFMA(af[ks], bfr, acc[q8]);
      }
    }
    #pragma unroll
    for (int q8=0;q8<8;q8++){
      int col = ntb*128 + q8*16 + lr;
      float bb = fc1b[col];
      #pragma unroll
      for (int j=0;j<4;j++){
        int tl = wm*16 + lg*4 + j;
        h[(t0+tl)*512 + col] = (bf16)(acc[q8][j] + bb);
      }
    }
  }
}

// ---------------- kernel 4: dwconv3x3 + GELU + fc2 + residual ------------
__global__ __launch_bounds__(256) void k_mlp2(
    const bf16* __restrict__ h, const float* __restrict__ dww, const float* __restrict__ dwb,
    const bf16* __restrict__ wf2, const float* __restrict__ fc2b,
    const float* __restrict__ x1, float* __restrict__ outx)
{
  __shared__ __align__(16) bf16 s_hh[100*128];
  __shared__ __align__(16) bf16 s_a [64*128];
  int tid = threadIdx.x, wm = tid>>6, l = tid&63;
  int lr = l & 15, lg = l >> 4;
  int tile = blockIdx.x, b = blockIdx.y;
  int ty = tile / 24, tx = tile % 24;
  int cq = (tid & 31) * 4;     // channel quad
  int tg = tid >> 5;           // token group of 8

  f32x4 acc[8];
  #pragma unroll
  for (int q=0;q<8;q++) acc[q] = zero_f4();

  for (int kc=0;kc<4;kc++){
    // stage 10x10 halo of this 128-ch chunk
    for (int it=0; it<7; it++){
      int idx = it*256 + tid;
      if (idx < 1600){
        int pos = idx>>4, c0 = (idx&15)*8;
        int hy = pos/10, hx = pos%10;
        int yy = ty*8 + hy - 1, xx = tx*8 + hx - 1;
        bf8 v;
        if (yy>=0 && yy<IMG && xx>=0 && xx<IMG)
          v = *(const bf8*)(h + ((size_t)b*HW + yy*IMG + xx)*512 + kc*128 + c0);
        else v = zero_bf8();
        *(bf8*)&s_hh[pos*128 + c0] = v;
      }
    }
    __syncthreads();
    // depthwise conv + bias + exact GELU -> s_a (swizzled bf16)
    {
      float w4a[4][9], bias4[4];
      #pragma unroll
      for (int c=0;c<4;c++){
        int chg = kc*128 + cq + c;
        #pragma unroll
        for (int q=0;q<9;q++) w4a[c][q] = dww[chg*9+q];
        bias4[c] = dwb[chg];
      }
      #pragma unroll
      for (int i=0;i<8;i++){
        int tok = tg*8 + i;
        int iy = tok>>3, ix = tok&7;
        float s4[4] = {bias4[0],bias4[1],bias4[2],bias4[3]};
        #pragma unroll
        for (int dy=0;dy<3;dy++){
          #pragma unroll
          for (int dx=0;dx<3;dx++){
            const bf16* pp = &s_hh[((iy+dy)*10 + ix+dx)*128 + cq];
            #pragma unroll
            for (int c=0;c<4;c++) s4[c] += (float)pp[c] * w4a[c][dy*3+dx];
          }
        }
        union { unsigned long long u; bf16 hh[4]; } pk4;
        #pragma unroll
        for (int c=0;c<4;c++){
          float g = 0.5f*s4[c]*(1.0f + erff(s4[c]*0.70710678118654752f));
          pk4.hh[c] = (bf16)g;
        }
        *(unsigned long long*)&s_a[swz128(tok,cq)] = pk4.u;
      }
    }
    __syncthreads();
    // fc2 partial GEMM for this K-chunk
    {
      bf8 af[4];
      #pragma unroll
      for (int ks=0;ks<4;ks++) af[ks] = *(const bf8*)&s_a[swz128(wm*16+lr, ks*32 + lg*8)];
      #pragma unroll
      for (int q=0;q<8;q++){
        #pragma unroll
        for (int ks=0;ks<4;ks++){
          bf8 bfr = *(const bf8*)(wf2 + (size_t)(q*16+lr)*512 + kc*128 + ks*32 + lg*8);
          acc[q] = MFMA(af[ks], bfr, acc[q]);
        }
      }
    }
    __syncthreads();
  }
  // epilogue: + fc2_b + residual(x1) -> out (f32)
  #pragma unroll
  for (int q=0;q<8;q++){
    int col = q*16 + lr;
    float bb = fc2b[col];
    #pragma unroll
    for (int j=0;j<4;j++){
      int tok = wm*16 + lg*4 + j;
      int yy = ty*8 + (tok>>3), xx = tx*8 + (tok&7);
      size_t addr = ((size_t)b*HW + yy*IMG + xx)*128 + col;
      outx[addr] = acc[q][j] + bb + x1[addr];
    }
  }
}

// ---------------- launcher ----------------
extern "C" void kernel_launch(void* const* d_in, const int* in_sizes, int n_in,
                              void* d_out, int out_size, void* d_ws, size_t ws_size,
                              hipStream_t stream)
{
  const float* x      = (const float*)d_in[0];
  const float* cor    = (const float*)d_in[1];
  const float* q_w    = (const float*)d_in[2];
  const float* kv_w   = (const float*)d_in[3];
  const float* cor_w  = (const float*)d_in[4];
  const float* proj_w = (const float*)d_in[5];
  const float* proj_b = (const float*)d_in[6];
  const float* mproj_w= (const float*)d_in[7];
  const float* mproj_b= (const float*)d_in[8];
  const float* n1w    = (const float*)d_in[9];
  const float* n1b    = (const float*)d_in[10];
  const float* n2w    = (const float*)d_in[11];
  const float* n2b    = (const float*)d_in[12];
  const float* fc1w   = (const float*)d_in[13];
  const float* fc1b   = (const float*)d_in[14];
  const float* dww    = (const float*)d_in[15];
  const float* dwb    = (const float*)d_in[16];
  const float* fc2w   = (const float*)d_in[17];
  const float* fc2b   = (const float*)d_in[18];
  float* out = (float*)d_out;

  char* ws = (char*)d_ws;
  bf16* wq  = (bf16*)(ws + 0);
  bf16* wkv = (bf16*)(ws + 32768);
  bf16* wpj = (bf16*)(ws + 98304);
  bf16* wmp = (bf16*)(ws + 131072);
  bf16* wf1 = (bf16*)(ws + 163840);
  bf16* wf2 = (bf16*)(ws + 294912);
  bf16* xn  = (bf16*)(ws + 425984);
  bf16* cew = (bf16*)(ws + 425984 + 37748736);
  float* x1 = (float*)(ws + 425984 + 2u*37748736);
  bf16* hbuf= (bf16*)(ws + 425984 + 2u*37748736 + 75497472);

  k_cvt<<<64,  256, 0, stream>>>(q_w,   wq,  16384);
  k_cvt<<<128, 256, 0, stream>>>(kv_w,  wkv, 32768);
  k_cvt<<<64,  256, 0, stream>>>(proj_w,wpj, 16384);
  k_cvt<<<64,  256, 0, stream>>>(mproj_w,wmp,16384);
  k_cvt<<<256, 256, 0, stream>>>(fc1w,  wf1, 65536);
  k_cvt<<<256, 256, 0, stream>>>(fc2w,  wf2, 65536);

  k_ln1 <<<T_TOT/4, 256, 0, stream>>>(x, cor, cor_w, n1w, n1b, xn, cew);
  k_attn<<<NWB,     256, 0, stream>>>(xn, cew, wq, wkv, wpj, wmp, proj_b, mproj_b,
                                      x, x1, out + (size_t)T_TOT*128);
  k_fc1 <<<T_TOT/64,256, 0, stream>>>(x1, n2w, n2b, wf1, fc1b, hbuf);
  k_mlp2<<<dim3(576,4), 256, 0, stream>>>(hbuf, dww, dwb, wf2, fc2b, x1, out);
}

// Round 2
// 679.300 us; speedup vs baseline: 1.0741x; 1.0741x over previous
//
#include <hip/hip_runtime.h>
#include <hip/hip_bf16.h>
#include <math.h>

#define NB 4
#define IMG 192
#define HW (IMG*IMG)        // 36864
#define T_TOT (NB*HW)       // 147456
#define HID 512
#define NWB 2304            // total windows
#define WPB 576             // windows per batch
#define NWS 24              // windows per side

typedef __bf16 bf16;
typedef __bf16 bf8 __attribute__((ext_vector_type(8)));
typedef float f32x4 __attribute__((ext_vector_type(4)));

#define MFMA(a,b,c) __builtin_amdgcn_mfma_f32_16x16x32_bf16(a,b,c,0,0,0)

__device__ __forceinline__ int swz128(int row, int col){ return row*128 + (col ^ ((row&7)<<3)); }

__device__ __forceinline__ bf8 zero_bf8(){
  bf8 z = { (bf16)0.f,(bf16)0.f,(bf16)0.f,(bf16)0.f,(bf16)0.f,(bf16)0.f,(bf16)0.f,(bf16)0.f };
  return z;
}
__device__ __forceinline__ f32x4 zero_f4(){ f32x4 z = {0.f,0.f,0.f,0.f}; return z; }

// ---------------- kernel 0: f32 -> bf16 weight conversion ----------------
__global__ void k_cvt(const float* __restrict__ s, bf16* __restrict__ d, int n){
  int i = blockIdx.x*256 + threadIdx.x;
  if (i < n) d[i] = (bf16)s[i];
}

// ---------------- kernel 1: LN1 + window partition + ce ------------------
__global__ __launch_bounds__(256) void k_ln1(
    const float* __restrict__ x, const float* __restrict__ cor,
    const float* __restrict__ cor_w, const float* __restrict__ n1w, const float* __restrict__ n1b,
    bf16* __restrict__ xn, bf16* __restrict__ ce)
{
  int wm = threadIdx.x >> 6, l = threadIdx.x & 63;
  int t = blockIdx.x*4 + wm;
  float2 xv = *(const float2*)(x + (size_t)t*128 + 2*l);
  float s = xv.x + xv.y, sq = xv.x*xv.x + xv.y*xv.y;
  #pragma unroll
  for (int m=1;m<64;m<<=1){ s += __shfl_xor(s,m,64); sq += __shfl_xor(sq,m,64); }
  float mean = s * (1.0f/128.0f);
  float var  = sq * (1.0f/128.0f) - mean*mean;
  float rstd = rsqrtf(var + 1e-5f);
  int c = 2*l;
  float y0 = (xv.x-mean)*rstd*n1w[c]   + n1b[c];
  float y1 = (xv.y-mean)*rstd*n1w[c+1] + n1b[c+1];

  int b = t / HW, r = t % HW;
  int yy = r / IMG, xx = r % IMG;
  int win = b*WPB + (yy>>3)*NWS + (xx>>3);
  int n = ((yy&7)<<3) + (xx&7);
  size_t base = (size_t)win*8192 + n*128 + c;

  union { unsigned int u; bf16 h[2]; } pk;
  pk.h[0] = (bf16)y0; pk.h[1] = (bf16)y1;
  *(unsigned int*)(xn + base) = pk.u;

  float c0 = cor[(size_t)t*2], c1 = cor[(size_t)t*2+1];
  float4 w4 = *(const float4*)(cor_w + 4*l);
  pk.h[0] = (bf16)(c0*w4.x + c1*w4.y);
  pk.h[1] = (bf16)(c0*w4.z + c1*w4.w);
  *(unsigned int*)(ce + base) = pk.u;
}

// ---------------- kernel 2: fused window attention -----------------------
// LDS 72KB -> 2 blocks/CU (was 120KB -> 1 block/CU).
// s_s: stage(xr) -> stage(xw) -> q (in-place) -> xo (in-place per head)
// s_k: k -> cm (after barrier)
__global__ __launch_bounds__(256) void k_attn(
    const bf16* __restrict__ xn, const bf16* __restrict__ ce,
    const bf16* __restrict__ wq, const bf16* __restrict__ wkv,
    const bf16* __restrict__ wpj, const bf16* __restrict__ wmp,
    const float* __restrict__ proj_b, const float* __restrict__ mproj_b,
    const float* __restrict__ x_in, float* __restrict__ x1, float* __restrict__ out_m)
{
  __shared__ __align__(16) bf16 s_s [64*128];
  __shared__ __align__(16) bf16 s_k [64*128];
  __shared__ __align__(16) bf16 s_vT[128*64];
  __shared__ __align__(16) bf16 s_ceT[128*64];
  __shared__ __align__(16) bf16 s_P [64*64];

  int tid = threadIdx.x, wm = tid>>6, l = tid&63;
  int lr = l & 15, lg = l >> 4;
  int win = blockIdx.x;
  int partner = (win + NWB/2) % NWB;
  const bf16* xw_g = xn + (size_t)win*8192;
  const bf16* xr_g = xn + (size_t)partner*8192;
  const bf16* ce_g = ce + (size_t)win*8192;

  // ---- issue all global loads early (xr, ce, xw) ----
  bf8 xrv[4], cev[4], xwv[4];
  #pragma unroll
  for (int tci=0;tci<4;tci++){
    int chunk = tid + tci*256;
    int row = chunk>>4, c0 = (chunk&15)*8;
    xrv[tci] = *(const bf8*)(xr_g + row*128 + c0);
    cev[tci] = *(const bf8*)(ce_g + row*128 + c0);
    xwv[tci] = *(const bf8*)(xw_g + row*128 + c0);
  }
  // ---- stage xr (swizzled) + ceT (transposed, swizzled) ----
  #pragma unroll
  for (int tci=0;tci<4;tci++){
    int chunk = tid + tci*256;
    int row = chunk>>4, c0 = (chunk&15)*8;
    *(bf8*)&s_s[swz128(row,c0)] = xrv[tci];
    #pragma unroll
    for (int i=0;i<8;i++){
      int chc = c0 + i;
      s_ceT[chc*64 + (row ^ ((chc&7)<<3))] = cev[tci][i];
    }
  }
  __syncthreads();

  // ---- kv GEMM: k -> s_k, v -> s_vT(transposed) ----
  {
    bf8 af[4];
    #pragma unroll
    for (int ks=0;ks<4;ks++) af[ks] = *(const bf8*)&s_s[swz128(wm*16+lr, ks*32 + lg*8)];
    #pragma unroll
    for (int nt=0;nt<8;nt++){
      f32x4 acc = zero_f4();
      #pragma unroll
      for (int ks=0;ks<4;ks++){
        bf8 bfr = *(const bf8*)(wkv + (nt*16+lr)*128 + ks*32 + lg*8);
        acc = MFMA(af[ks], bfr, acc);
      }
      #pragma unroll
      for (int j=0;j<4;j++){
        int row = wm*16 + lg*4 + j;
        s_k[swz128(row, nt*16+lr)] = (bf16)acc[j];
      }
    }
    #pragma unroll
    for (int nt=0;nt<8;nt++){
      f32x4 acc = zero_f4();
      #pragma unroll
      for (int ks=0;ks<4;ks++){
        bf8 bfr = *(const bf8*)(wkv + (128 + nt*16+lr)*128 + ks*32 + lg*8);
        acc = MFMA(af[ks], bfr, acc);
      }
      #pragma unroll
      for (int j=0;j<4;j++){
        int tok = wm*16 + lg*4 + j;
        int chc = nt*16 + lr;
        s_vT[chc*64 + (tok ^ ((chc&7)<<3))] = (bf16)acc[j];
      }
    }
  }
  __syncthreads();

  // ---- stage xw into s_s (from regs, loads issued long ago) ----
  #pragma unroll
  for (int tci=0;tci<4;tci++){
    int chunk = tid + tci*256;
    int row = chunk>>4, c0 = (chunk&15)*8;
    *(bf8*)&s_s[swz128(row,c0)] = xwv[tci];
  }
  __syncthreads();

  // ---- q GEMM in-place (each wave: read own 16 rows -> regs, write own 16 rows) ----
  {
    bf8 af[4];
    #pragma unroll
    for (int ks=0;ks<4;ks++) af[ks] = *(const bf8*)&s_s[swz128(wm*16+lr, ks*32 + lg*8)];
    #pragma unroll
    for (int nt=0;nt<8;nt++){
      f32x4 acc = zero_f4();
      #pragma unroll
      for (int ks=0;ks<4;ks++){
        bf8 bfr = *(const bf8*)(wq + (nt*16+lr)*128 + ks*32 + lg*8);
        acc = MFMA(af[ks], bfr, acc);
      }
      #pragma unroll
      for (int j=0;j<4;j++){
        int row = wm*16 + lg*4 + j;
        s_s[swz128(row, nt*16+lr)] = (bf16)acc[j];
      }
    }
  }

  // ---- head loop (barrier-free; cm accumulator in registers) ----
  const float scale = 0.25f;
  float accC[8][4];
  #pragma unroll
  for (int h=0;h<8;h++){
    bf8 aS;
    if (l < 32) aS = *(const bf8*)&s_s[swz128(wm*16+lr, h*16 + lg*8)];
    else        aS = zero_bf8();
    f32x4 accS[4];
    #pragma unroll
    for (int nt=0;nt<4;nt++){
      bf8 bS;
      if (l < 32) bS = *(const bf8*)&s_k[swz128(nt*16+lr, h*16 + lg*8)];
      else        bS = zero_bf8();
      accS[nt] = MFMA(aS, bS, zero_f4());
    }
    float rs4[4];
    #pragma unroll
    for (int j=0;j<4;j++){
      float v0 = accS[0][j]*scale, v1 = accS[1][j]*scale;
      float v2 = accS[2][j]*scale, v3 = accS[3][j]*scale;
      float mx = fmaxf(fmaxf(v0,v1), fmaxf(v2,v3));
      mx = fmaxf(mx, __shfl_xor(mx,1,64));
      mx = fmaxf(mx, __shfl_xor(mx,2,64));
      mx = fmaxf(mx, __shfl_xor(mx,4,64));
      mx = fmaxf(mx, __shfl_xor(mx,8,64));
      float e0 = __expf(v0-mx), e1 = __expf(v1-mx), e2 = __expf(v2-mx), e3 = __expf(v3-mx);
      float sm = e0+e1+e2+e3;
      sm += __shfl_xor(sm,1,64); sm += __shfl_xor(sm,2,64);
      sm += __shfl_xor(sm,4,64); sm += __shfl_xor(sm,8,64);
      rs4[j] = 1.0f / sm;
      int row = wm*16 + lg*4 + j;
      s_P[row*64 + ((lr+ 0) ^ ((row&7)<<3))] = (bf16)e0;
      s_P[row*64 + ((lr+16) ^ ((row&7)<<3))] = (bf16)e1;
      s_P[row*64 + ((lr+32) ^ ((row&7)<<3))] = (bf16)e2;
      s_P[row*64 + ((lr+48) ^ ((row&7)<<3))] = (bf16)e3;
    }
    f32x4 accO = zero_f4(), accCt = zero_f4();
    #pragma unroll
    for (int ks=0;ks<2;ks++){
      int rowA = wm*16 + lr;
      bf8 aP = *(const bf8*)&s_P[rowA*64 + ((ks*32 + lg*8) ^ ((rowA&7)<<3))];
      int chc = h*16 + lr;
      bf8 bV = *(const bf8*)&s_vT [chc*64 + ((ks*32 + lg*8) ^ ((chc&7)<<3))];
      accO = MFMA(aP, bV, accO);
      bf8 bC = *(const bf8*)&s_ceT[chc*64 + ((ks*32 + lg*8) ^ ((chc&7)<<3))];
      accCt = MFMA(aP, bC, accCt);
    }
    #pragma unroll
    for (int j=0;j<4;j++){
      int row = wm*16 + lg*4 + j;
      s_s[swz128(row, h*16+lr)] = (bf16)(accO[j]*rs4[j]);   // xo in-place over q
      accC[h][j] = accCt[j]*rs4[j];
    }
  }

  // ---- proj (+residual, window-reverse): reads own rows of s_s (xo) ----
  int b  = win / WPB, wi = win % WPB;
  int wy = wi / NWS,  wx = wi % NWS;
  {
    bf8 af[4];
    #pragma unroll
    for (int ks=0;ks<4;ks++) af[ks] = *(const bf8*)&s_s[swz128(wm*16+lr, ks*32 + lg*8)];
    #pragma unroll
    for (int nt=0;nt<8;nt++){
      f32x4 acc = zero_f4();
      #pragma unroll
      for (int ks=0;ks<4;ks++){
        bf8 bfr = *(const bf8*)(wpj + (nt*16+lr)*128 + ks*32 + lg*8);
        acc = MFMA(af[ks], bfr, acc);
      }
      int col = nt*16 + lr;
      float pb = proj_b[col];
      #pragma unroll
      for (int j=0;j<4;j++){
        int tok = wm*16 + lg*4 + j;
        int yy = wy*8 + (tok>>3), xx = wx*8 + (tok&7);
        size_t addr = ((size_t)b*HW + yy*IMG + xx)*128 + col;
        x1[addr] = acc[j] + pb + x_in[addr];
      }
    }
  }
  __syncthreads();   // all waves done reading s_k (head loop) before cm overwrite

  // ---- cm = accC - ce  ->  s_k (own rows), then mproj ----
  #pragma unroll
  for (int h=0;h<8;h++){
    #pragma unroll
    for (int j=0;j<4;j++){
      int row = wm*16 + lg*4 + j;
      int chc = h*16 + lr;
      float cef = (float)s_ceT[chc*64 + (row ^ ((chc&7)<<3))];
      s_k[swz128(row, chc)] = (bf16)(accC[h][j] - cef);
    }
  }
  {
    bf8 af[4];
    #pragma unroll
    for (int ks=0;ks<4;ks++) af[ks] = *(const bf8*)&s_k[swz128(wm*16+lr, ks*32 + lg*8)];
    #pragma unroll
    for (int nt=0;nt<8;nt++){
      f32x4 acc = zero_f4();
      #pragma unroll
      for (int ks=0;ks<4;ks++){
        bf8 bfr = *(const bf8*)(wmp + (nt*16+lr)*128 + ks*32 + lg*8);
        acc = MFMA(af[ks], bfr, acc);
      }
      int col = nt*16 + lr;
      float pb = mproj_b[col];
      #pragma unroll
      for (int j=0;j<4;j++){
        int tok = wm*16 + lg*4 + j;
        int yy = wy*8 + (tok>>3), xx = wx*8 + (tok&7);
        size_t addr = ((size_t)b*HW + yy*IMG + xx)*128 + col;
        out_m[addr] = acc[j] + pb;
      }
    }
  }
}

// ---------------- kernel 3: LN2 + fc1 ------------------------------------
__global__ __launch_bounds__(256) void k_fc1(
    const float* __restrict__ x1, const float* __restrict__ n2w, const float* __restrict__ n2b,
    const bf16* __restrict__ wf1, const float* __restrict__ fc1b, bf16* __restrict__ h)
{
  __shared__ __align__(16) bf16 s_a[64*128];
  int tid = threadIdx.x, wm = tid>>6, l = tid&63;
  int lr = l & 15, lg = l >> 4;
  size_t t0 = (size_t)blockIdx.x * 64;

  for (int i=0;i<16;i++){
    int tl = wm*16 + i;
    float2 xv = *(const float2*)(x1 + (t0+tl)*128 + 2*l);
    float s = xv.x+xv.y, sq = xv.x*xv.x+xv.y*xv.y;
    #pragma unroll
    for (int m=1;m<64;m<<=1){ s += __shfl_xor(s,m,64); sq += __shfl_xor(sq,m,64); }
    float mean = s*(1.f/128.f), var = sq*(1.f/128.f) - mean*mean;
    float rstd = rsqrtf(var + 1e-5f);
    int c = 2*l;
    union { unsigned int u; bf16 hh[2]; } pk;
    pk.hh[0] = (bf16)((xv.x-mean)*rstd*n2w[c]   + n2b[c]);
    pk.hh[1] = (bf16)((xv.y-mean)*rstd*n2w[c+1] + n2b[c+1]);
    *(unsigned int*)&s_a[swz128(tl,c)] = pk.u;
  }
  __syncthreads();

  bf8 af[4];
  #pragma unroll
  for (int ks=0;ks<4;ks++) af[ks] = *(const bf8*)&s_a[swz128(wm*16+lr, ks*32 + lg*8)];
  for (int ntb=0; ntb<4; ntb++){
    f32x4 acc[8];
    #pragma unroll
    for (int q8=0;q8<8;q8++){
      acc[q8] = zero_f4();
      #pragma unroll
      for (int ks=0;ks<4;ks++){
        int ocol = ntb*128 + q8*16 + lr;
        bf8 bfr = *(const bf8*)(wf1 + (size_t)ocol*128 + ks*32 + lg*8);
        acc[q8] = MFMA(af[ks], bfr, acc[q8]);
      }
    }
    #pragma unroll
    for (int q8=0;q8<8;q8++){
      int col = ntb*128 + q8*16 + lr;
      float bb = fc1b[col];
      #pragma unroll
      for (int j=0;j<4;j++){
        int tl = wm*16 + lg*4 + j;
        h[(t0+tl)*512 + col] = (bf16)(acc[q8][j] + bb);
      }
    }
  }
}

// ---------------- kernel 4: dwconv3x3 + GELU + fc2 + residual ------------
__global__ __launch_bounds__(256) void k_mlp2(
    const bf16* __restrict__ h, const float* __restrict__ dww, const float* __restrict__ dwb,
    const bf16* __restrict__ wf2, const float* __restrict__ fc2b,
    const float* __restrict__ x1, float* __restrict__ outx)
{
  __shared__ __align__(16) bf16 s_hh[100*128];
  __shared__ __align__(16) bf16 s_a [64*128];
  int tid = threadIdx.x, wm = tid>>6, l = tid&63;
  int lr = l & 15, lg = l >> 4;
  int tile = blockIdx.x, b = blockIdx.y;
  int ty = tile / 24, tx = tile % 24;
  int cq = (tid & 31) * 4;     // channel quad
  int tg = tid >> 5;           // token group of 8

  f32x4 acc[8];
  #pragma unroll
  for (int q=0;q<8;q++) acc[q] = zero_f4();

  for (int kc=0;kc<4;kc++){
    for (int it=0; it<7; it++){
      int idx = it*256 + tid;
      if (idx < 1600){
        int pos = idx>>4, c0 = (idx&15)*8;
        int hy = pos/10, hx = pos%10;
        int yy = ty*8 + hy - 1, xx = tx*8 + hx - 1;
        bf8 v;
        if (yy>=0 && yy<IMG && xx>=0 && xx<IMG)
          v = *(const bf8*)(h + ((size_t)b*HW + yy*IMG + xx)*512 + kc*128 + c0);
        else v = zero_bf8();
        *(bf8*)&s_hh[pos*128 + c0] = v;
      }
    }
    __syncthreads();
    {
      float w4a[4][9], bias4[4];
      #pragma unroll
      for (int c=0;c<4;c++){
        int chg = kc*128 + cq + c;
        #pragma unroll
        for (int q=0;q<9;q++) w4a[c][q] = dww[chg*9+q];
        bias4[c] = dwb[chg];
      }
      #pragma unroll
      for (int i=0;i<8;i++){
        int tok = tg*8 + i;
        int iy = tok>>3, ix = tok&7;
        float s4[4] = {bias4[0],bias4[1],bias4[2],bias4[3]};
        #pragma unroll
        for (int dy=0;dy<3;dy++){
          #pragma unroll
          for (int dx=0;dx<3;dx++){
            const bf16* pp = &s_hh[((iy+dy)*10 + ix+dx)*128 + cq];
            #pragma unroll
            for (int c=0;c<4;c++) s4[c] += (float)pp[c] * w4a[c][dy*3+dx];
          }
        }
        union { unsigned long long u; bf16 hh[4]; } pk4;
        #pragma unroll
        for (int c=0;c<4;c++){
          float g = 0.5f*s4[c]*(1.0f + erff(s4[c]*0.70710678118654752f));
          pk4.hh[c] = (bf16)g;
        }
        *(unsigned long long*)&s_a[swz128(tok,cq)] = pk4.u;
      }
    }
    __syncthreads();
    {
      bf8 af[4];
      #pragma unroll
      for (int ks=0;ks<4;ks++) af[ks] = *(const bf8*)&s_a[swz128(wm*16+lr, ks*32 + lg*8)];
      #pragma unroll
      for (int q=0;q<8;q++){
        #pragma unroll
        for (int ks=0;ks<4;ks++){
          bf8 bfr = *(const bf8*)(wf2 + (size_t)(q*16+lr)*512 + kc*128 + ks*32 + lg*8);
          acc[q] = MFMA(af[ks], bfr, acc[q]);
        }
      }
    }
    __syncthreads();
  }
  #pragma unroll
  for (int q=0;q<8;q++){
    int col = q*16 + lr;
    float bb = fc2b[col];
    #pragma unroll
    for (int j=0;j<4;j++){
      int tok = wm*16 + lg*4 + j;
      int yy = ty*8 + (tok>>3), xx = tx*8 + (tok&7);
      size_t addr = ((size_t)b*HW + yy*IMG + xx)*128 + col;
      outx[addr] = acc[q][j] + bb + x1[addr];
    }
  }
}

// ---------------- launcher ----------------
extern "C" void kernel_launch(void* const* d_in, const int* in_sizes, int n_in,
                              void* d_out, int out_size, void* d_ws, size_t ws_size,
                              hipStream_t stream)
{
  const float* x      = (const float*)d_in[0];
  const float* cor    = (const float*)d_in[1];
  const float* q_w    = (const float*)d_in[2];
  const float* kv_w   = (const float*)d_in[3];
  const float* cor_w  = (const float*)d_in[4];
  const float* proj_w = (const float*)d_in[5];
  const float* proj_b = (const float*)d_in[6];
  const float* mproj_w= (const float*)d_in[7];
  const float* mproj_b= (const float*)d_in[8];
  const float* n1w    = (const float*)d_in[9];
  const float* n1b    = (const float*)d_in[10];
  const float* n2w    = (const float*)d_in[11];
  const float* n2b    = (const float*)d_in[12];
  const float* fc1w   = (const float*)d_in[13];
  const float* fc1b   = (const float*)d_in[14];
  const float* dww    = (const float*)d_in[15];
  const float* dwb    = (const float*)d_in[16];
  const float* fc2w   = (const float*)d_in[17];
  const float* fc2b   = (const float*)d_in[18];
  float* out = (float*)d_out;

  char* ws = (char*)d_ws;
  bf16* wq  = (bf16*)(ws + 0);
  bf16* wkv = (bf16*)(ws + 32768);
  bf16* wpj = (bf16*)(ws + 98304);
  bf16* wmp = (bf16*)(ws + 131072);
  bf16* wf1 = (bf16*)(ws + 163840);
  bf16* wf2 = (bf16*)(ws + 294912);
  bf16* xn  = (bf16*)(ws + 425984);
  bf16* cew = (bf16*)(ws + 425984 + 37748736);
  float* x1 = (float*)(ws + 425984 + 2u*37748736);
  bf16* hbuf= (bf16*)(ws + 425984 + 2u*37748736 + 75497472);

  k_cvt<<<64,  256, 0, stream>>>(q_w,   wq,  16384);
  k_cvt<<<128, 256, 0, stream>>>(kv_w,  wkv, 32768);
  k_cvt<<<64,  256, 0, stream>>>(proj_w,wpj, 16384);
  k_cvt<<<64,  256, 0, stream>>>(mproj_w,wmp,16384);
  k_cvt<<<256, 256, 0, stream>>>(fc1w,  wf1, 65536);
  k_cvt<<<256, 256, 0, stream>>>(fc2w,  wf2, 65536);

  k_ln1 <<<T_TOT/4, 256, 0, stream>>>(x, cor, cor_w, n1w, n1b, xn, cew);
  k_attn<<<NWB,     256, 0, stream>>>(xn, cew, wq, wkv, wpj, wmp, proj_b, mproj_b,
                                      x, x1, out + (size_t)T_TOT*128);
  k_fc1 <<<T_TOT/64,256, 0, stream>>>(x1, n2w, n2b, wf1, fc1b, hbuf);
  k_mlp2<<<dim3(576,4), 256, 0, stream>>>(hbuf, dww, dwb, wf2, fc2b, x1, out);
}

// Round 3
// 559.817 us; speedup vs baseline: 1.3034x; 1.2134x over previous
//
#include <hip/hip_runtime.h>
#include <hip/hip_bf16.h>
#include <math.h>

#define NB 4
#define IMG 192
#define HW (IMG*IMG)        // 36864
#define T_TOT (NB*HW)       // 147456
#define HID 512
#define NWB 2304            // total windows
#define WPB 576             // windows per batch
#define NWS 24              // windows per side

typedef __bf16 bf16;
typedef __bf16 bf8 __attribute__((ext_vector_type(8)));
typedef __bf16 bf4 __attribute__((ext_vector_type(4)));
typedef float f32x4 __attribute__((ext_vector_type(4)));

#define MFMA(a,b,c) __builtin_amdgcn_mfma_f32_16x16x32_bf16(a,b,c,0,0,0)

__device__ __forceinline__ int swz128(int row, int col){ return row*128 + (col ^ ((row&7)<<3)); }

__device__ __forceinline__ bf8 zero_bf8(){
  bf8 z = { (bf16)0.f,(bf16)0.f,(bf16)0.f,(bf16)0.f,(bf16)0.f,(bf16)0.f,(bf16)0.f,(bf16)0.f };
  return z;
}
__device__ __forceinline__ f32x4 zero_f4(){ f32x4 z = {0.f,0.f,0.f,0.f}; return z; }

// ---------------- kernel 0: f32 -> bf16 weight conversion (with scale) ---
__global__ void k_cvt(const float* __restrict__ s, bf16* __restrict__ d, int n, float scale){
  int i = blockIdx.x*256 + threadIdx.x;
  if (i < n) d[i] = (bf16)(s[i]*scale);
}

// ---------------- kernel 0b: A2 = mproj_w @ blockdiag(cor_w) -------------
// a2w[o][2h+c] = sum_i mproj_w[o,h*16+i] * cor_w[h*16+i,c]; padded to [128][32]
__global__ void k_a2(const float* __restrict__ mproj_w, const float* __restrict__ cor_w,
                     bf16* __restrict__ a2w){
  int idx = blockIdx.x*256 + threadIdx.x;
  if (idx >= 4096) return;
  int o = idx >> 5, k = idx & 31;
  float acc = 0.f;
  if (k < 16){
    int h = k >> 1, c = k & 1;
    #pragma unroll
    for (int i=0;i<16;i++)
      acc += mproj_w[o*128 + h*16 + i] * cor_w[(h*16+i)*2 + c];
  }
  a2w[o*32 + k] = (bf16)acc;
}

// ---------------- kernel 1: LN1 + window partition + windowed cor --------
// 16 lanes per token; block = 16 tokens
__global__ __launch_bounds__(256) void k_ln1(
    const float* __restrict__ x, const float* __restrict__ cor,
    const float* __restrict__ n1w, const float* __restrict__ n1b,
    bf16* __restrict__ xn, bf16* __restrict__ cwb)
{
  int tid = threadIdx.x, wm = tid>>6, l = tid&63;
  int lr = l & 15, tg = l >> 4;
  int t = blockIdx.x*16 + wm*4 + tg;

  const float* xp = x + (size_t)t*128 + lr*8;
  float4 a = *(const float4*)xp;
  float4 b4 = *(const float4*)(xp+4);
  float s  = a.x+a.y+a.z+a.w + b4.x+b4.y+b4.z+b4.w;
  float sq = a.x*a.x+a.y*a.y+a.z*a.z+a.w*a.w + b4.x*b4.x+b4.y*b4.y+b4.z*b4.z+b4.w*b4.w;
  #pragma unroll
  for (int m=1;m<16;m<<=1){ s += __shfl_xor(s,m,16); sq += __shfl_xor(sq,m,16); }
  float mean = s * (1.0f/128.0f);
  float var  = sq * (1.0f/128.0f) - mean*mean;
  float rstd = rsqrtf(var + 1e-5f);

  float4 nw0 = *(const float4*)(n1w + lr*8), nw1 = *(const float4*)(n1w + lr*8 + 4);
  float4 nb0 = *(const float4*)(n1b + lr*8), nb1 = *(const float4*)(n1b + lr*8 + 4);

  bf8 o;
  o[0] = (bf16)((a.x -mean)*rstd*nw0.x + nb0.x);
  o[1] = (bf16)((a.y -mean)*rstd*nw0.y + nb0.y);
  o[2] = (bf16)((a.z -mean)*rstd*nw0.z + nb0.z);
  o[3] = (bf16)((a.w -mean)*rstd*nw0.w + nb0.w);
  o[4] = (bf16)((b4.x-mean)*rstd*nw1.x + nb1.x);
  o[5] = (bf16)((b4.y-mean)*rstd*nw1.y + nb1.y);
  o[6] = (bf16)((b4.z-mean)*rstd*nw1.z + nb1.z);
  o[7] = (bf16)((b4.w-mean)*rstd*nw1.w + nb1.w);

  int b = t / HW, r = t % HW;
  int yy = r / IMG, xx = r % IMG;
  int win = b*WPB + (yy>>3)*NWS + (xx>>3);
  int n = ((yy&7)<<3) + (xx&7);
  *(bf8*)(xn + (size_t)win*8192 + n*128 + lr*8) = o;

  if (lr < 2) cwb[(size_t)win*128 + n*2 + lr] = (bf16)cor[(size_t)t*2 + lr];
}

// ---------------- kernel 2: fused window attention -----------------------
// s_s: stage(xr) -> stage(xw) -> q (in-place) -> xo (in-place per head)
// motion branch collapsed to rank-2: D = P@[cor|1]/rs - cor; out = D @ A2^T
__global__ __launch_bounds__(256) void k_attn(
    const bf16* __restrict__ xn, const bf16* __restrict__ cw,
    const bf16* __restrict__ wq, const bf16* __restrict__ wkv,
    const bf16* __restrict__ wpj, const bf16* __restrict__ a2w,
    const float* __restrict__ proj_b, const float* __restrict__ mproj_b,
    const float* __restrict__ x_in, float* __restrict__ x1, float* __restrict__ out_m)
{
  __shared__ __align__(16) bf16 s_s [64*128];
  __shared__ __align__(16) bf16 s_k [64*128];
  __shared__ __align__(16) bf16 s_vT[128*64];
  __shared__ __align__(16) bf16 s_P [2][64*64];
  __shared__ __align__(16) bf16 s_cT[16*64];
  __shared__ __align__(16) bf16 s_D [64*32];

  int tid = threadIdx.x, wm = tid>>6, l = tid&63;
  int lr = l & 15, lg = l >> 4;
  int win = blockIdx.x;
  int partner = (win + NWB/2) % NWB;
  const bf16* xw_g = xn + (size_t)win*8192;
  const bf16* xr_g = xn + (size_t)partner*8192;

  // ---- issue global loads early ----
  bf8 xrv[4], xwv[4];
  #pragma unroll
  for (int tci=0;tci<4;tci++){
    int chunk = tid + tci*256;
    int row = chunk>>4, c0 = (chunk&15)*8;
    xrv[tci] = *(const bf8*)(xr_g + row*128 + c0);
    xwv[tci] = *(const bf8*)(xw_g + row*128 + c0);
  }
  bf16 cwv = (bf16)0.f;
  if (tid < 128) cwv = cw[(size_t)win*128 + tid];

  // ---- phase 1: zero s_cT/s_D, stage xr ----
  *(unsigned long long*)&s_cT[tid*4] = 0ull;
  *(unsigned long long*)&s_D[tid*8]   = 0ull;
  *(unsigned long long*)&s_D[tid*8+4] = 0ull;
  #pragma unroll
  for (int tci=0;tci<4;tci++){
    int chunk = tid + tci*256;
    int row = chunk>>4, c0 = (chunk&15)*8;
    *(bf8*)&s_s[swz128(row,c0)] = xrv[tci];
  }
  __syncthreads();

  // ---- phase 2: kv GEMM + corT fill ----
  if (tid < 128){
    int c = tid & 1, m = tid >> 1;
    s_cT[c*64 + (m ^ (c<<3))] = cwv;
  } else if (tid < 192){
    int m = tid - 128;
    s_cT[2*64 + (m ^ 16)] = (bf16)1.0f;
  }
  {
    bf8 af[4];
    #pragma unroll
    for (int ks=0;ks<4;ks++) af[ks] = *(const bf8*)&s_s[swz128(wm*16+lr, ks*32 + lg*8)];
    #pragma unroll
    for (int nt=0;nt<8;nt++){
      f32x4 acc = zero_f4();
      #pragma unroll
      for (int ks=0;ks<4;ks++){
        bf8 bfr = *(const bf8*)(wkv + (nt*16+lr)*128 + ks*32 + lg*8);
        acc = MFMA(af[ks], bfr, acc);
      }
      #pragma unroll
      for (int j=0;j<4;j++){
        int row = wm*16 + lg*4 + j;
        s_k[swz128(row, nt*16+lr)] = (bf16)acc[j];
      }
    }
    #pragma unroll
    for (int nt=0;nt<8;nt++){
      f32x4 acc = zero_f4();
      #pragma unroll
      for (int ks=0;ks<4;ks++){
        bf8 bfr = *(const bf8*)(wkv + (128 + nt*16+lr)*128 + ks*32 + lg*8);
        acc = MFMA(af[ks], bfr, acc);
      }
      #pragma unroll
      for (int j=0;j<4;j++){
        int tok = wm*16 + lg*4 + j;
        int chc = nt*16 + lr;
        s_vT[chc*64 + (tok ^ ((chc&7)<<3))] = (bf16)acc[j];
      }
    }
  }
  __syncthreads();

  // ---- phase 3: stage xw ----
  #pragma unroll
  for (int tci=0;tci<4;tci++){
    int chunk = tid + tci*256;
    int row = chunk>>4, c0 = (chunk&15)*8;
    *(bf8*)&s_s[swz128(row,c0)] = xwv[tci];
  }
  __syncthreads();

  // ---- phase 4: q GEMM in-place (scale folded into wq) ----
  {
    bf8 af[4];
    #pragma unroll
    for (int ks=0;ks<4;ks++) af[ks] = *(const bf8*)&s_s[swz128(wm*16+lr, ks*32 + lg*8)];
    #pragma unroll
    for (int nt=0;nt<8;nt++){
      f32x4 acc = zero_f4();
      #pragma unroll
      for (int ks=0;ks<4;ks++){
        bf8 bfr = *(const bf8*)(wq + (nt*16+lr)*128 + ks*32 + lg*8);
        acc = MFMA(af[ks], bfr, acc);
      }
      #pragma unroll
      for (int j=0;j<4;j++){
        int row = wm*16 + lg*4 + j;
        s_s[swz128(row, nt*16+lr)] = (bf16)acc[j];
      }
    }
  }

  float mycw[4] = {0.f,0.f,0.f,0.f};
  if (lr < 2){
    #pragma unroll
    for (int j=0;j<4;j++){
      int row = wm*16 + lg*4 + j;
      mycw[j] = (float)s_cT[lr*64 + (row ^ (lr<<3))];
    }
  }

  // ---- head loop: no max-sub, unnormalized e; rowsum via MFMA col 2 ----
  #pragma unroll
  for (int h=0;h<8;h++){
    bf8 aS = zero_bf8();
    if (l < 32) aS = *(const bf8*)&s_s[swz128(wm*16+lr, h*16 + lg*8)];
    f32x4 accS[4];
    #pragma unroll
    for (int nt=0;nt<4;nt++){
      bf8 bSv = zero_bf8();
      if (l < 32) bSv = *(const bf8*)&s_k[swz128(nt*16+lr, h*16 + lg*8)];
      accS[nt] = MFMA(aS, bSv, zero_f4());
    }
    bf16* Pb = &s_P[h&1][0];
    #pragma unroll
    for (int nt=0;nt<4;nt++){
      #pragma unroll
      for (int j=0;j<4;j++){
        int row = wm*16 + lg*4 + j;
        Pb[row*64 + ((nt*16+lr) ^ ((row&7)<<3))] = (bf16)__expf(accS[nt][j]);
      }
    }
    f32x4 accO = zero_f4(), accPC = zero_f4();
    #pragma unroll
    for (int ks=0;ks<2;ks++){
      int rowA = wm*16 + lr;
      bf8 aP = *(const bf8*)&Pb[rowA*64 + ((ks*32 + lg*8) ^ ((rowA&7)<<3))];
      int chc = h*16 + lr;
      bf8 bV = *(const bf8*)&s_vT[chc*64 + ((ks*32 + lg*8) ^ ((chc&7)<<3))];
      accO = MFMA(aP, bV, accO);
      bf8 bC = *(const bf8*)&s_cT[lr*64 + ((ks*32 + lg*8) ^ ((lr&7)<<3))];
      accPC = MFMA(aP, bC, accPC);
    }
    #pragma unroll
    for (int j=0;j<4;j++){
      int row = wm*16 + lg*4 + j;
      float rs = __shfl(accPC[j], (l & 48) + 2, 64);
      float inv = __builtin_amdgcn_rcpf(rs);
      s_s[swz128(row, h*16+lr)] = (bf16)(accO[j]*inv);
      if (lr < 2)
        s_D[row*32 + ((2*h+lr) ^ ((row&3)<<3))] = (bf16)(accPC[j]*inv - mycw[j]);
    }
  }

  // ---- proj (+residual, window-reverse) ----
  int b  = win / WPB, wi = win % WPB;
  int wy = wi / NWS,  wx = wi % NWS;
  {
    bf8 af[4];
    #pragma unroll
    for (int ks=0;ks<4;ks++) af[ks] = *(const bf8*)&s_s[swz128(wm*16+lr, ks*32 + lg*8)];
    #pragma unroll
    for (int nt=0;nt<8;nt++){
      f32x4 acc = zero_f4();
      #pragma unroll
      for (int ks=0;ks<4;ks++){
        bf8 bfr = *(const bf8*)(wpj + (nt*16+lr)*128 + ks*32 + lg*8);
        acc = MFMA(af[ks], bfr, acc);
      }
      int col = nt*16 + lr;
      float pb = proj_b[col];
      #pragma unroll
      for (int j=0;j<4;j++){
        int tok = wm*16 + lg*4 + j;
        int yy = wy*8 + (tok>>3), xx = wx*8 + (tok&7);
        size_t addr = ((size_t)b*HW + yy*IMG + xx)*128 + col;
        x1[addr] = acc[j] + pb + x_in[addr];
      }
    }
  }
  // ---- motion: out_m = D @ A2^T + mb ----
  {
    int rowA = wm*16 + lr;
    bf8 afD = *(const bf8*)&s_D[rowA*32 + ((lg*8) ^ ((rowA&3)<<3))];
    #pragma unroll
    for (int nt=0;nt<8;nt++){
      bf8 bfr = *(const bf8*)(a2w + (nt*16+lr)*32 + lg*8);
      f32x4 acc = MFMA(afD, bfr, zero_f4());
      int col = nt*16 + lr;
      float pb = mproj_b[col];
      #pragma unroll
      for (int j=0;j<4;j++){
        int tok = wm*16 + lg*4 + j;
        int yy = wy*8 + (tok>>3), xx = wx*8 + (tok&7);
        size_t addr = ((size_t)b*HW + yy*IMG + xx)*128 + col;
        out_m[addr] = acc[j] + pb;
      }
    }
  }
}

// ---------------- kernel 3: LN2 + fc1 ------------------------------------
__global__ __launch_bounds__(256) void k_fc1(
    const float* __restrict__ x1, const float* __restrict__ n2w, const float* __restrict__ n2b,
    const bf16* __restrict__ wf1, const float* __restrict__ fc1b, bf16* __restrict__ h)
{
  __shared__ __align__(16) bf16 s_a[64*128];
  int tid = threadIdx.x, wm = tid>>6, l = tid&63;
  int lr = l & 15, lg = l >> 4;
  size_t t0 = (size_t)blockIdx.x * 64;

  float4 nw0 = *(const float4*)(n2w + lr*8), nw1 = *(const float4*)(n2w + lr*8 + 4);
  float4 nb0 = *(const float4*)(n2b + lr*8), nb1 = *(const float4*)(n2b + lr*8 + 4);

  #pragma unroll
  for (int rr=0; rr<4; rr++){
    int row = wm*16 + rr*4 + lg;
    const float* xp = x1 + (t0+row)*128 + lr*8;
    float4 a = *(const float4*)xp;
    float4 b4 = *(const float4*)(xp+4);
    float s  = a.x+a.y+a.z+a.w + b4.x+b4.y+b4.z+b4.w;
    float sq = a.x*a.x+a.y*a.y+a.z*a.z+a.w*a.w + b4.x*b4.x+b4.y*b4.y+b4.z*b4.z+b4.w*b4.w;
    #pragma unroll
    for (int m=1;m<16;m<<=1){ s += __shfl_xor(s,m,16); sq += __shfl_xor(sq,m,16); }
    float mean = s*(1.f/128.f), var = sq*(1.f/128.f) - mean*mean;
    float rstd = rsqrtf(var + 1e-5f);
    bf8 o;
    o[0] = (bf16)((a.x -mean)*rstd*nw0.x + nb0.x);
    o[1] = (bf16)((a.y -mean)*rstd*nw0.y + nb0.y);
    o[2] = (bf16)((a.z -mean)*rstd*nw0.z + nb0.z);
    o[3] = (bf16)((a.w -mean)*rstd*nw0.w + nb0.w);
    o[4] = (bf16)((b4.x-mean)*rstd*nw1.x + nb1.x);
    o[5] = (bf16)((b4.y-mean)*rstd*nw1.y + nb1.y);
    o[6] = (bf16)((b4.z-mean)*rstd*nw1.z + nb1.z);
    o[7] = (bf16)((b4.w-mean)*rstd*nw1.w + nb1.w);
    *(bf8*)&s_a[swz128(row, lr*8)] = o;
  }
  __syncthreads();

  bf8 af[4];
  #pragma unroll
  for (int ks=0;ks<4;ks++) af[ks] = *(const bf8*)&s_a[swz128(wm*16+lr, ks*32 + lg*8)];
  for (int ntb=0; ntb<4; ntb++){
    f32x4 acc[8];
    #pragma unroll
    for (int q8=0;q8<8;q8++){
      acc[q8] = zero_f4();
      #pragma unroll
      for (int ks=0;ks<4;ks++){
        int ocol = ntb*128 + q8*16 + lr;
        bf8 bfr = *(const bf8*)(wf1 + (size_t)ocol*128 + ks*32 + lg*8);
        acc[q8] = MFMA(af[ks], bfr, acc[q8]);
      }
    }
    #pragma unroll
    for (int q8=0;q8<8;q8++){
      int col = ntb*128 + q8*16 + lr;
      float bb = fc1b[col];
      #pragma unroll
      for (int j=0;j<4;j++){
        int tl = wm*16 + lg*4 + j;
        h[(t0+tl)*512 + col] = (bf16)(acc[q8][j] + bb);
      }
    }
  }
}

// ---------------- kernel 4: dwconv3x3 + GELU + fc2 + residual ------------
__global__ __launch_bounds__(256) void k_mlp2(
    const bf16* __restrict__ h, const float* __restrict__ dww, const float* __restrict__ dwb,
    const bf16* __restrict__ wf2, const float* __restrict__ fc2b,
    const float* __restrict__ x1, float* __restrict__ outx)
{
  __shared__ __align__(16) bf16 s_hh[100*128];
  __shared__ __align__(16) bf16 s_a [64*128];
  int tid = threadIdx.x, wm = tid>>6, l = tid&63;
  int lr = l & 15, lg = l >> 4;
  int tile = blockIdx.x, b = blockIdx.y;
  int ty = tile / 24, tx = tile % 24;
  int cq = (tid & 31) * 4;     // channel quad
  int tg = tid >> 5;           // token group of 8

  f32x4 acc[8];
  #pragma unroll
  for (int q=0;q<8;q++) acc[q] = zero_f4();

  for (int kc=0;kc<4;kc++){
    for (int it=0; it<7; it++){
      int idx = it*256 + tid;
      if (idx < 1600){
        int pos = idx>>4, c0 = (idx&15)*8;
        int hy = pos/10, hx = pos%10;
        int yy = ty*8 + hy - 1, xx = tx*8 + hx - 1;
        bf8 v;
        if (yy>=0 && yy<IMG && xx>=0 && xx<IMG)
          v = *(const bf8*)(h + ((size_t)b*HW + yy*IMG + xx)*512 + kc*128 + c0);
        else v = zero_bf8();
        *(bf8*)&s_hh[pos*128 + c0] = v;
      }
    }
    __syncthreads();
    {
      int chg0 = kc*128 + cq;
      float wflat[36];
      #pragma unroll
      for (int q=0;q<9;q++){
        float4 t4 = *(const float4*)(dww + chg0*9 + q*4);
        wflat[q*4+0]=t4.x; wflat[q*4+1]=t4.y; wflat[q*4+2]=t4.z; wflat[q*4+3]=t4.w;
      }
      float4 bias4 = *(const float4*)(dwb + chg0);
      float bb[4] = {bias4.x, bias4.y, bias4.z, bias4.w};
      #pragma unroll
      for (int i=0;i<8;i++){
        int tok = tg*8 + i;
        int iy = tok>>3, ix = tok&7;
        float s4[4] = {bb[0],bb[1],bb[2],bb[3]};
        #pragma unroll
        for (int dy=0;dy<3;dy++){
          #pragma unroll
          for (int dx=0;dx<3;dx++){
            bf4 pv = *(const bf4*)&s_hh[((iy+dy)*10 + ix+dx)*128 + cq];
            #pragma unroll
            for (int c=0;c<4;c++) s4[c] += (float)pv[c] * wflat[c*9 + dy*3+dx];
          }
        }
        bf4 g4;
        #pragma unroll
        for (int c=0;c<4;c++){
          float g = 0.5f*s4[c]*(1.0f + erff(s4[c]*0.70710678118654752f));
          g4[c] = (bf16)g;
        }
        *(bf4*)&s_a[swz128(tok,cq)] = g4;
      }
    }
    __syncthreads();
    {
      bf8 af[4];
      #pragma unroll
      for (int ks=0;ks<4;ks++) af[ks] = *(const bf8*)&s_a[swz128(wm*16+lr, ks*32 + lg*8)];
      #pragma unroll
      for (int q=0;q<8;q++){
        #pragma unroll
        for (int ks=0;ks<4;ks++){
          bf8 bfr = *(const bf8*)(wf2 + (size_t)(q*16+lr)*512 + kc*128 + ks*32 + lg*8);
          acc[q] = MFMA(af[ks], bfr, acc[q]);
        }
      }
    }
    __syncthreads();
  }
  #pragma unroll
  for (int q=0;q<8;q++){
    int col = q*16 + lr;
    float bb = fc2b[col];
    #pragma unroll
    for (int j=0;j<4;j++){
      int tok = wm*16 + lg*4 + j;
      int yy = ty*8 + (tok>>3), xx = tx*8 + (tok&7);
      size_t addr = ((size_t)b*HW + yy*IMG + xx)*128 + col;
      outx[addr] = acc[q][j] + bb + x1[addr];
    }
  }
}

// ---------------- launcher ----------------
extern "C" void kernel_launch(void* const* d_in, const int* in_sizes, int n_in,
                              void* d_out, int out_size, void* d_ws, size_t ws_size,
                              hipStream_t stream)
{
  const float* x      = (const float*)d_in[0];
  const float* cor    = (const float*)d_in[1];
  const float* q_w    = (const float*)d_in[2];
  const float* kv_w   = (const float*)d_in[3];
  const float* cor_w  = (const float*)d_in[4];
  const float* proj_w = (const float*)d_in[5];
  const float* proj_b = (const float*)d_in[6];
  const float* mproj_w= (const float*)d_in[7];
  const float* mproj_b= (const float*)d_in[8];
  const float* n1w    = (const float*)d_in[9];
  const float* n1b    = (const float*)d_in[10];
  const float* n2w    = (const float*)d_in[11];
  const float* n2b    = (const float*)d_in[12];
  const float* fc1w   = (const float*)d_in[13];
  const float* fc1b   = (const float*)d_in[14];
  const float* dww    = (const float*)d_in[15];
  const float* dwb    = (const float*)d_in[16];
  const float* fc2w   = (const float*)d_in[17];
  const float* fc2b   = (const float*)d_in[18];
  float* out = (float*)d_out;

  char* ws = (char*)d_ws;
  bf16* wq   = (bf16*)(ws + 0);          // 32768
  bf16* wkv  = (bf16*)(ws + 32768);      // 65536
  bf16* wpj  = (bf16*)(ws + 98304);      // 32768
  bf16* a2w  = (bf16*)(ws + 131072);     // 8192
  bf16* wf1  = (bf16*)(ws + 139264);     // 131072
  bf16* wf2  = (bf16*)(ws + 270336);     // 131072
  bf16* xn   = (bf16*)(ws + 401408);     // 37748736
  bf16* cwb  = (bf16*)(ws + 38150144);   // 589824
  float* x1  = (float*)(ws + 38739968);  // 75497472
  bf16* hbuf = (bf16*)(ws + 114237440);  // 150994944

  k_cvt<<<64,  256, 0, stream>>>(q_w,   wq,  16384, 0.25f);  // attn scale folded
  k_cvt<<<128, 256, 0, stream>>>(kv_w,  wkv, 32768, 1.0f);
  k_cvt<<<64,  256, 0, stream>>>(proj_w,wpj, 16384, 1.0f);
  k_cvt<<<256, 256, 0, stream>>>(fc1w,  wf1, 65536, 1.0f);
  k_cvt<<<256, 256, 0, stream>>>(fc2w,  wf2, 65536, 1.0f);
  k_a2 <<<16,  256, 0, stream>>>(mproj_w, cor_w, a2w);

  k_ln1 <<<T_TOT/16, 256, 0, stream>>>(x, cor, n1w, n1b, xn, cwb);
  k_attn<<<NWB,      256, 0, stream>>>(xn, cwb, wq, wkv, wpj, a2w, proj_b, mproj_b,
                                       x, x1, out + (size_t)T_TOT*128);
  k_fc1 <<<T_TOT/64, 256, 0, stream>>>(x1, n2w, n2b, wf1, fc1b, hbuf);
  k_mlp2<<<dim3(576,4), 256, 0, stream>>>(hbuf, dww, dwb, wf2, fc2b, x1, out);
}